// Round 20
// baseline (413.052 us; speedup 1.0000x reference)
//
#include <hip/hip_runtime.h>

#define N_GRAPHS 100000
#define NTYPES 8
#define MAXD 128
#define FEAT 256
#define ALDA 136   // As row stride, shorts (272B)

typedef __attribute__((ext_vector_type(8))) short short8;
typedef __attribute__((ext_vector_type(4))) float f32x4;
typedef __attribute__((ext_vector_type(4))) unsigned uint4v;

constexpr int KSN[NTYPES]  = {1, 1, 2, 4, 2, 1, 1, 4};
constexpr int DIMS[NTYPES] = {16, 32, 64, 128, 64, 32, 16, 128};

__device__ __forceinline__ unsigned f2bf_u(float f) {
    unsigned u = __builtin_bit_cast(unsigned, f);
    return (u + 0x7fffu + ((u >> 16) & 1u)) >> 16;   // round-to-nearest-even
}
__device__ __forceinline__ unsigned cvt2(float lo, float hi) {
    return f2bf_u(lo) | (f2bf_u(hi) << 16);
}
__device__ __forceinline__ short8 cvt8(f32x4 a, f32x4 b) {
    uint4v u;
    u.x = cvt2(a.x, a.y); u.y = cvt2(a.z, a.w);
    u.z = cvt2(b.x, b.y); u.w = cvt2(b.z, b.w);
    return __builtin_bit_cast(short8, u);
}

// --- W -> bf16 fragment prepack. wp[(((t*16 + ct)*4 + ks)*4 + cgrp)*16 + c16]
//     = W[t][ct*16 + c16][ks*32 + cgrp*8 .. +7], zero-masked at k >= dim.
// Same index map serves the MFMA A-operand (row = lane&15, k = (lane>>4)*8).
__global__ __launch_bounds__(256)
void prepack_w(const float* __restrict__ W, short8* __restrict__ wp)
{
    const int idx  = blockIdx.x * 256 + threadIdx.x;   // 32768
    const int c16  = idx & 15;
    const int cgrp = (idx >> 4) & 3;
    const int ks   = (idx >> 6) & 3;
    const int ct   = (idx >> 8) & 15;
    const int t    = (idx >> 12) & 7;
    const int col  = ct * 16 + c16;
    const int k    = ks * 32 + cgrp * 8;
    const int dim  = 16 << ((0x30123210u >> (4 * t)) & 0xf);
    const float* src = W + ((size_t)t * FEAT + col) * MAXD + k;
    f32x4 a = *(const f32x4*)src;
    f32x4 b = *(const f32x4*)(src + 4);
    #pragma unroll
    for (int j = 0; j < 4; ++j) {
        if (k + j     >= dim) a[j] = 0.f;
        if (k + 4 + j >= dim) b[j] = 0.f;
    }
    wp[idx] = cvt8(a, b);
}

// One type for one wave's 16 graphs. SWAPPED OPERANDS vs R12: A = W fragment,
// B = x fragment (identical fragment reads; only the mfma arg order flips).
// D: col = graph = c16, row = feat = cgrp*4 + r  -> each lane stores 4
// CONSECUTIVE feats of its graph as one plain dwordx4. NO Ep transpose, no
// scalar ds_writes, no flush chain. Plain stores let L2 merge the 64B-granule
// row visits into full lines (nt at this granularity amplified WRITE, R7).
template<int T, bool PRE>
__device__ __forceinline__ void do_type(const float* __restrict__ x,
                                        const short8* __restrict__ wp,
                                        const float* __restrict__ W,
                                        const float* __restrict__ bias_g,
                                        float* __restrict__ out,
                                        unsigned short* __restrict__ as_,
                                        int g0, int lane, int cgrp, int c16)
{
    constexpr int KS  = KSN[T];
    constexpr int NXT = (T + 1 < NTYPES) ? T + 1 : T;   // dummy on last type
    constexpr int KSn = KSN[NXT];
    constexpr int SPRn = KSn * 4;                       // 8-float segs per row

    // (1) T14 split: issue next type's x loads -> regs (vmcnt waits at step 4)
    f32x4 pv[2 * KSn];
    if constexpr (T + 1 < NTYPES) {
        #pragma unroll
        for (int p = 0; p < KSn; ++p) {
            const int idx = p * 64 + lane;
            const int row = idx / SPRn, s8 = idx % SPRn;
            const float* rp = x + (((size_t)(g0 + row)) * NTYPES + (T + 1)) * MAXD + s8 * 8;
            pv[2 * p]     = __builtin_nontemporal_load((const f32x4*)rp);
            pv[2 * p + 1] = __builtin_nontemporal_load((const f32x4*)rp + 1);
        }
    }

    // (2) B fragments (x): col = graph = c16, k = ks*32 + cgrp*8
    short8 xf[KS];
    #pragma unroll
    for (int ks = 0; ks < KS; ++ks)
        xf[ks] = *(const short8*)&as_[c16 * ALDA + ks * 32 + cgrp * 8];

    // (3) 16 feature-tiles; MFMA -> direct dwordx4 store (no LDS epilogue)
    const size_t orow = ((size_t)(g0 + c16) * NTYPES + T) * FEAT;
    #pragma unroll
    for (int ct = 0; ct < 16; ++ct) {
        short8 wf[KS];
        if constexpr (PRE) {
            #pragma unroll
            for (int ks = 0; ks < KS; ++ks)
                wf[ks] = wp[(((T * 16 + ct) * 4 + ks) * 4 + cgrp) * 16 + c16];
        } else {
            constexpr int DIM = DIMS[T];
            #pragma unroll
            for (int ks = 0; ks < KS; ++ks) {
                const int k = ks * 32 + cgrp * 8;
                const float* wfp = W + ((size_t)T * FEAT + ct * 16 + c16) * MAXD + k;
                f32x4 wa = *(const f32x4*)wfp;
                f32x4 wb = *(const f32x4*)(wfp + 4);
                #pragma unroll
                for (int j = 0; j < 4; ++j) {
                    if (k + j     >= DIM) wa[j] = 0.f;
                    if (k + 4 + j >= DIM) wb[j] = 0.f;
                }
                wf[ks] = cvt8(wa, wb);
            }
        }
        f32x4 acc = {0.f, 0.f, 0.f, 0.f};
        #pragma unroll
        for (int ks = 0; ks < KS; ++ks)
            acc = __builtin_amdgcn_mfma_f32_16x16x32_bf16(wf[ks], xf[ks], acc, 0, 0, 0);
        // D: col(graph) = c16, row(feat) = cgrp*4 + r  [m89 layout, swapped]
        const f32x4 b4 = *(const f32x4*)&bias_g[T * FEAT + ct * 16 + cgrp * 4];
        f32x4 res;
        #pragma unroll
        for (int r = 0; r < 4; ++r) res[r] = acc[r] + b4[r];
        *(f32x4*)&out[orow + ct * 16 + cgrp * 4] = res;   // plain, L2-merging
    }

    // (4) vmcnt-wait prefetched x, cvt, ds_write into As (frags already in regs)
    if constexpr (T + 1 < NTYPES) {
        #pragma unroll
        for (int p = 0; p < KSn; ++p) {
            const int idx = p * 64 + lane;
            const int row = idx / SPRn, s8 = idx % SPRn;
            *(short8*)&as_[row * ALDA + s8 * 8] = cvt8(pv[2 * p], pv[2 * p + 1]);
        }
        do_type<T + 1, PRE>(x, wp, W, bias_g, out, as_, g0, lane, cgrp, c16);
    }
}

// 4 independent waves per block, 16 graphs each (100000 = 6250x16; surplus
// waves exit whole). Zero __syncthreads; As-only LDS (17.4 KB/block) ->
// 4 blocks/CU at launch_bounds(256,4) = 16 waves/CU.
template<bool PRE>
__global__ __launch_bounds__(256, 4)
void node_enc(const float* __restrict__ x, const short8* __restrict__ wp,
              const float* __restrict__ W, const float* __restrict__ bias_g,
              float* __restrict__ out)
{
    __shared__ __align__(16) unsigned short As[4][16 * ALDA];  // 17408 B
    const int tid  = threadIdx.x;
    const int lane = tid & 63;
    const int wave = tid >> 6;
    const int cgrp = lane >> 4;
    const int c16  = lane & 15;
    const int w    = blockIdx.x * 4 + wave;
    if (w >= N_GRAPHS / 16) return;   // whole-wave exit (last block only)
    const int g0   = w * 16;

    unsigned short* as_ = As[wave];
    // prologue: stage type 0 (KS=1 -> one pass: 16 rows x 4 segs)
    {
        const int row = lane >> 2, s8 = lane & 3;
        const float* rp = x + (((size_t)(g0 + row)) * NTYPES + 0) * MAXD + s8 * 8;
        f32x4 v0 = __builtin_nontemporal_load((const f32x4*)rp);
        f32x4 v1 = __builtin_nontemporal_load((const f32x4*)rp + 1);
        *(short8*)&as_[row * ALDA + s8 * 8] = cvt8(v0, v1);
    }

    do_type<0, PRE>(x, wp, W, bias_g, out, as_, g0, lane, cgrp, c16);
}

extern "C" void kernel_launch(void* const* d_in, const int* in_sizes, int n_in,
                              void* d_out, int out_size, void* d_ws, size_t ws_size,
                              hipStream_t stream)
{
    const float* x = (const float*)d_in[0];
    const float* W = (const float*)d_in[1];
    const float* b = (const float*)d_in[2];
    float* out = (float*)d_out;

    const int grid = (N_GRAPHS / 16 + 3) / 4;                 // 1563
    const size_t wp_bytes = (size_t)32768 * sizeof(short8);   // 512 KB

    if (ws_size >= wp_bytes) {
        short8* wp = (short8*)d_ws;
        prepack_w<<<128, 256, 0, stream>>>(W, wp);
        node_enc<true><<<grid, 256, 0, stream>>>(x, wp, W, b, out);
    } else {
        node_enc<false><<<grid, 256, 0, stream>>>(x, nullptr, W, b, out);
    }
}